// Round 2
// baseline (278.631 us; speedup 1.0000x reference)
//
#include <hip/hip_runtime.h>
#include <hip/hip_bf16.h>

#define C_DIM 128
#define SCALE 0.17677669529663687f

typedef __attribute__((ext_vector_type(8))) short frag8;
typedef __attribute__((ext_vector_type(4))) float f32x4;

// ---- LDS (ushort units), 25216 total = 50432 B -> 3 blocks/CU ----
// Single 25216-ushort arena:
//  * Staging: x bf16 rows 0..48 (stride 136, 6800 ushorts at base 0). xf goes
//    to regs before barrier (2), then the arena is dead as x.
//  * Phase A..C: per-head wave-PRIVATE regions at h*6304 (heads 0/1 overlay
//    dead x): Q 50x40 (row 49 trash), K 50x40, Vt 32x72 (cols 49..63 garbage,
//    cancelled by P zeros). P 50x72 overlays Q+K once qf/kf are in regs.
//  * Phase D: act rows 0..49 stride 136 overlays head regions after barrier (3).
// Pad tokens: reads clamp to row 48; writes go to trash row 49; softmax guards
// j<49; P cols >=49 explicitly 0.
#define XACT_STR 136
#define HEAD_SZ  6304
#define KOFF 2000
#define VOFF 4000
#define Q_STR 40
#define VT_STR 72
#define P_STR 72
#define SMEM_TOT 25216

__device__ __forceinline__ unsigned short f2b(float x) {
    __hip_bfloat16 h = __float2bfloat16(x);
    return __builtin_bit_cast(unsigned short, h);
}
__device__ __forceinline__ unsigned pk2(float a, float b) {
    return ((unsigned)f2b(b) << 16) | (unsigned)f2b(a);
}
__device__ __forceinline__ void add4(f32x4& a, float4 m) {
    a[0] += m.x; a[1] += m.y; a[2] += m.z; a[3] += m.w;
}

// fp32 weights -> bf16 ws: [0,49152) qkv_w, [49152,65536) proj_w
__global__ void convert_weights(const float4* __restrict__ qkvw,
                                const float4* __restrict__ projw,
                                ushort4* __restrict__ wbf) {
    int i = blockIdx.x * 256 + threadIdx.x;
    float4 v = (i < 12288) ? qkvw[i] : projw[i - 12288];
    ushort4 p;
    p.x = f2b(v.x); p.y = f2b(v.y); p.z = f2b(v.z); p.w = f2b(v.w);
    wbf[i] = p;
}

// mask[64][49][49] fp32 -> pm[64][49][64] fp32 (cols 49..63 = 0).
// Row stride 64 floats = 256 B so every 16B-chunk is aligned -> dwordx4 loads.
__global__ void pad_mask(const float* __restrict__ mask, float* __restrict__ pm) {
    int t = blockIdx.x * 256 + threadIdx.x;      // 196*256 = 50176 exactly
    int w = t / 784, rem = t % 784, i = rem >> 4, tq = rem & 15;
    const float* src = mask + (size_t)w * 2401 + i * 49;
    int j = tq * 4;
    float4 v;
    v.x = (j     < 49) ? src[j]     : 0.f;
    v.y = (j + 1 < 49) ? src[j + 1] : 0.f;
    v.z = (j + 2 < 49) ? src[j + 2] : 0.f;
    v.w = (j + 3 < 49) ? src[j + 3] : 0.f;
    ((float4*)pm)[t] = v;
}

__global__ __launch_bounds__(256, 3) void attn_mfma(
    const float* __restrict__ x,
    const float* __restrict__ pmask,
    const float* __restrict__ qkv_b,
    const float* __restrict__ proj_b,
    const unsigned short* __restrict__ wq,
    float* __restrict__ out)
{
    __shared__ __align__(16) unsigned short sm[SMEM_TOT];

    const int b = blockIdx.x, tid = threadIdx.x;
    const int h    = tid >> 6;   // wave = head, owns the full chain
    const int lane = tid & 63;
    const int n16  = lane & 15;
    const int q    = lane >> 4;

    // ---- hoisted proj weights + all biases (overlap x staging latency) ----
    const unsigned short* pw = wq + 49152;
    frag8 wf2[2][4];
#pragma unroll
    for (int ct = 0; ct < 2; ++ct)
#pragma unroll
        for (int ks = 0; ks < 4; ++ks)
            wf2[ct][ks] = *(const frag8*)(pw + (size_t)(h * 32 + ct * 16 + n16) * C_DIM + ks * 32 + q * 8);
    float4 pb4[2];
    float4 b4m[2][2];   // qkv bias for Q,K (per mat, ct)
    float  bV[2];       // V bias (per ct, indexed by n16)
#pragma unroll
    for (int ct = 0; ct < 2; ++ct) {
        pb4[ct] = *(const float4*)(proj_b + h * 32 + ct * 16 + q * 4);
#pragma unroll
        for (int mat = 0; mat < 2; ++mat)
            b4m[mat][ct] = *(const float4*)(qkv_b + mat * C_DIM + h * 32 + ct * 16 + q * 4);
        bV[ct] = qkv_b[2 * C_DIM + h * 32 + ct * 16 + n16];
    }

    // ---- stage x[b] rows 0..48 -> bf16 (base 0, stride 136) ----
    {
        const float4* xg = (const float4*)(x + (size_t)b * 6272);
        for (int i = tid; i < 1568; i += 256) {
            float4 v = xg[i];
            int row = i >> 5, col = (i & 31) << 2;
            uint2 pk; pk.x = pk2(v.x, v.y); pk.y = pk2(v.z, v.w);
            *(uint2*)&sm[row * XACT_STR + col] = pk;
        }
    }
    __syncthreads();  // (1) x staged

    // ---- x frags, pad rows clamp to row 48 ----
    frag8 xf[4][4];
#pragma unroll
    for (int tt = 0; tt < 4; ++tt)
#pragma unroll
        for (int ks = 0; ks < 4; ++ks)
            xf[tt][ks] = *(const frag8*)&sm[min(tt * 16 + n16, 48) * XACT_STR + ks * 32 + q * 8];
    __syncthreads();  // (2) x in regs everywhere -> head regions may overlay staging

    const int Hb = h * HEAD_SZ;

    // ---- Phase A: QKV, wave-private epilogues, NO barriers ----
#pragma unroll
    for (int mat = 0; mat < 3; ++mat) {
#pragma unroll
        for (int ct = 0; ct < 2; ++ct) {
            const unsigned short* wrow = wq + (size_t)(mat * C_DIM + h * 32 + ct * 16 + n16) * C_DIM;
            frag8 wf[4];
#pragma unroll
            for (int ks = 0; ks < 4; ++ks) wf[ks] = *(const frag8*)(wrow + ks * 32 + q * 8);
            if (mat < 2) {
                // D = W x^T: row=ch(q*4+r), col=tok(n16) -> Q/K[tok][ch] packed
                float4 b4 = b4m[mat][ct];
                const float sc = (mat == 0) ? SCALE : 1.f;
                const int base = Hb + ((mat == 0) ? 0 : KOFF);
#pragma unroll
                for (int tt = 0; tt < 4; ++tt) {
                    f32x4 acc = {0.f, 0.f, 0.f, 0.f};
#pragma unroll
                    for (int ks = 0; ks < 4; ++ks)
                        acc = __builtin_amdgcn_mfma_f32_16x16x32_bf16(wf[ks], xf[tt][ks], acc, 0, 0, 0);
                    uint2 pk;
                    pk.x = pk2((acc[0] + b4.x) * sc, (acc[1] + b4.y) * sc);
                    pk.y = pk2((acc[2] + b4.z) * sc, (acc[3] + b4.w) * sc);
                    *(uint2*)&sm[base + min(tt * 16 + n16, 49) * Q_STR + ct * 16 + q * 4] = pk;
                }
            } else {
                // V: D = x W^T: row=tok(q*4+r), col=ch(n16) -> Vt[ch][tok] packed
                float bias = bV[ct];
#pragma unroll
                for (int tt = 0; tt < 4; ++tt) {
                    f32x4 acc = {0.f, 0.f, 0.f, 0.f};
#pragma unroll
                    for (int ks = 0; ks < 4; ++ks)
                        acc = __builtin_amdgcn_mfma_f32_16x16x32_bf16(xf[tt][ks], wf[ks], acc, 0, 0, 0);
                    uint2 pk;
                    pk.x = pk2(acc[0] + bias, acc[1] + bias);
                    pk.y = pk2(acc[2] + bias, acc[3] + bias);
                    *(uint2*)&sm[Hb + VOFF + (ct * 16 + n16) * VT_STR + tt * 16 + q * 4] = pk;
                }
            }
        }
    }

    // ---- Phase B: S^T = K Q^T, zero C-init (mask added in softmax) ----
    frag8 qf[4], kf[4];
#pragma unroll
    for (int t = 0; t < 4; ++t) {
        qf[t] = *(const frag8*)&sm[Hb + (t * 16 + n16) * Q_STR + q * 8];
        kf[t] = *(const frag8*)&sm[Hb + KOFF + (t * 16 + n16) * Q_STR + q * 8];
    }
    f32x4 s[4][4];   // [jt][it]
#pragma unroll
    for (int jt = 0; jt < 4; ++jt)
#pragma unroll
        for (int it = 0; it < 4; ++it)
            s[jt][it] = (f32x4){0.f, 0.f, 0.f, 0.f};
#pragma unroll
    for (int jt = 0; jt < 4; ++jt)
#pragma unroll
        for (int it = 0; it < 4; ++it)
            s[jt][it] = __builtin_amdgcn_mfma_f32_16x16x32_bf16(kf[jt], qf[it], s[jt][it], 0, 0, 0);

    // ---- softmax + mask add + P writes (P overlays Q+K; qf/kf in regs) ----
    // Padded mask: row i at pmrow + i*64, 16B-aligned dwordx4 loads; cols
    // 49..63 are zero so unconditional adds are safe (invalid j guarded below).
    const float* pmrow = pmask + (size_t)(b & 63) * 3136;
#pragma unroll
    for (int it = 0; it < 4; ++it) {
        int ii = min(it * 16 + n16, 48);
        const float* mp = pmrow + ii * 64 + q * 4;
        float4 m0 = *(const float4*)(mp);
        float4 m1 = *(const float4*)(mp + 16);
        float4 m2 = *(const float4*)(mp + 32);
        float4 m3 = *(const float4*)(mp + 48);
        add4(s[0][it], m0); add4(s[1][it], m1);
        add4(s[2][it], m2); add4(s[3][it], m3);

        float val[16];
#pragma unroll
        for (int jt = 0; jt < 4; ++jt)
#pragma unroll
            for (int r = 0; r < 4; ++r)
                val[jt * 4 + r] = (jt * 16 + q * 4 + r < 49) ? s[jt][it][r] : -1e30f;
#pragma unroll
        for (int st = 8; st >= 1; st >>= 1)
#pragma unroll
            for (int k = 0; k < 8; ++k)
                if (k < st) val[k] = fmaxf(val[k], val[k + st]);
        float mx = val[0];
        mx = fmaxf(mx, __shfl_xor(mx, 16));
        mx = fmaxf(mx, __shfl_xor(mx, 32));

        float ev[16];
#pragma unroll
        for (int jt = 0; jt < 4; ++jt)
#pragma unroll
            for (int r = 0; r < 4; ++r) {
                float e = (jt * 16 + q * 4 + r < 49) ? __expf(s[jt][it][r] - mx) : 0.f;
                s[jt][it][r] = e;
                ev[jt * 4 + r] = e;
            }
#pragma unroll
        for (int st = 8; st >= 1; st >>= 1)
#pragma unroll
            for (int k = 0; k < 8; ++k)
                if (k < st) ev[k] += ev[k + st];
        float sum = ev[0];
        sum += __shfl_xor(sum, 16);
        sum += __shfl_xor(sum, 32);
        float inv = __builtin_amdgcn_rcpf(sum);
#pragma unroll
        for (int jt = 0; jt < 4; ++jt) {
            uint2 pk;
            pk.x = pk2(s[jt][it][0] * inv, s[jt][it][1] * inv);
            pk.y = pk2(s[jt][it][2] * inv, s[jt][it][3] * inv);
            *(uint2*)&sm[Hb + min(it * 16 + n16, 49) * P_STR + jt * 16 + q * 4] = pk;
        }
    }

    // ---- Phase C: O^T = Vt P^T (all LDS reads hoisted -> one wait point) ----
    frag8 vf[2][2];
#pragma unroll
    for (int ct = 0; ct < 2; ++ct)
#pragma unroll
        for (int ks = 0; ks < 2; ++ks)
            vf[ct][ks] = *(const frag8*)&sm[Hb + VOFF + (ct * 16 + n16) * VT_STR + ks * 32 + q * 8];
    frag8 pfa[4][2];
#pragma unroll
    for (int nt = 0; nt < 4; ++nt)
#pragma unroll
        for (int ks = 0; ks < 2; ++ks)
            pfa[nt][ks] = *(const frag8*)&sm[Hb + min(nt * 16 + n16, 49) * P_STR + ks * 32 + q * 8];
    f32x4 o[2][4];
#pragma unroll
    for (int ct = 0; ct < 2; ++ct)
#pragma unroll
        for (int nt = 0; nt < 4; ++nt) o[ct][nt] = (f32x4){0.f, 0.f, 0.f, 0.f};
#pragma unroll
    for (int nt = 0; nt < 4; ++nt)
#pragma unroll
        for (int ks = 0; ks < 2; ++ks)
#pragma unroll
            for (int ct = 0; ct < 2; ++ct)
                o[ct][nt] = __builtin_amdgcn_mfma_f32_16x16x32_bf16(vf[ct][ks], pfa[nt][ks], o[ct][nt], 0, 0, 0);
    __syncthreads();  // (3) all Phase C LDS reads retired -> act may overlay head regions

    // ---- act[tok][128ch] rows 0..49 stride 136 (row 49 = trash for pad toks) ----
#pragma unroll
    for (int ct = 0; ct < 2; ++ct)
#pragma unroll
        for (int nt = 0; nt < 4; ++nt) {
            uint2 pk;
            pk.x = pk2(o[ct][nt][0], o[ct][nt][1]);
            pk.y = pk2(o[ct][nt][2], o[ct][nt][3]);
            *(uint2*)&sm[min(nt * 16 + n16, 49) * XACT_STR + h * 32 + ct * 16 + q * 4] = pk;
        }
    __syncthreads();  // (4) act complete

    // ---- Phase D: out^T = W act^T (all af reads hoisted -> one wait point) ----
    float* outb = out + (size_t)b * 6272;
    frag8 af[4][4];
#pragma unroll
    for (int nt = 0; nt < 4; ++nt)
#pragma unroll
        for (int ks = 0; ks < 4; ++ks)
            af[nt][ks] = *(const frag8*)&sm[min(nt * 16 + n16, 48) * XACT_STR + ks * 32 + q * 8];
#pragma unroll
    for (int nt = 0; nt < 4; ++nt) {
        int tok = nt * 16 + n16;
#pragma unroll
        for (int ct = 0; ct < 2; ++ct) {
            f32x4 acc = {0.f, 0.f, 0.f, 0.f};
#pragma unroll
            for (int ks = 0; ks < 4; ++ks)
                acc = __builtin_amdgcn_mfma_f32_16x16x32_bf16(wf2[ct][ks], af[nt][ks], acc, 0, 0, 0);
            if (tok < 49)
                *(float4*)&outb[tok * C_DIM + h * 32 + ct * 16 + q * 4] =
                    make_float4(acc[0] + pb4[ct].x, acc[1] + pb4[ct].y,
                                acc[2] + pb4[ct].z, acc[3] + pb4[ct].w);
        }
    }
}

extern "C" void kernel_launch(void* const* d_in, const int* in_sizes, int n_in,
                              void* d_out, int out_size, void* d_ws, size_t ws_size,
                              hipStream_t stream) {
    const float* x      = (const float*)d_in[0];
    const float* mask   = (const float*)d_in[1];
    const float* qkv_b  = (const float*)d_in[3];
    const float* proj_b = (const float*)d_in[5];

    unsigned short* wbf = (unsigned short*)d_ws;                   // 131072 B
    float* pmask = (float*)((char*)d_ws + 131072);                 // 802816 B
    convert_weights<<<64, 256, 0, stream>>>((const float4*)d_in[2],
                                            (const float4*)d_in[4],
                                            (ushort4*)wbf);
    pad_mask<<<196, 256, 0, stream>>>(mask, pmask);
    attn_mfma<<<4096, 256, 0, stream>>>(x, pmask, qkv_b, proj_b, wbf, (float*)d_out);
}